// Round 9
// baseline (5213.535 us; speedup 1.0000x reference)
//
#include <hip/hip_runtime.h>

#define LOG2E 1.4426950408889634f

__device__ __forceinline__ unsigned short f2bf(float f) {
  unsigned u = __float_as_uint(f);
  u += 0x7FFFu + ((u >> 16) & 1u);            // round-to-nearest-even
  return (unsigned short)(u >> 16);
}
__device__ __forceinline__ unsigned pk2(float a, float b) {
  return (unsigned)f2bf(a) | ((unsigned)f2bf(b) << 16);
}
__device__ __forceinline__ float bl16(unsigned u) { return __uint_as_float(u << 16); }
__device__ __forceinline__ float bh16(unsigned u) { return __uint_as_float(u & 0xFFFF0000u); }

// Load + pin: the volatile asm defines the value; it cannot be rematerialized,
// so the result MUST stay in a VGPR for its entire live range (the whole loop).
__device__ __forceinline__ float pinned_load(const float* p) {
  float x = *p;
  asm volatile("" : "+v"(x));
  return x;
}

// LDS-visibility barrier WITHOUT the vmcnt(0) drain __syncthreads would emit.
__device__ __forceinline__ void lds_barrier() {
  asm volatile("s_waitcnt lgkmcnt(0)" ::: "memory");
  __builtin_amdgcn_s_barrier();
}

// DPP cross-lane adds (VALU pipe): reduce over 8 consecutive lanes.
__device__ __forceinline__ float dpp_xor1_add(float x) {
  return x + __int_as_float(__builtin_amdgcn_update_dpp(
      0, __float_as_int(x), 0xB1, 0xF, 0xF, true));
}
__device__ __forceinline__ float dpp_xor2_add(float x) {
  return x + __int_as_float(__builtin_amdgcn_update_dpp(
      0, __float_as_int(x), 0x4E, 0xF, 0xF, true));
}
__device__ __forceinline__ float dpp_xor7_add(float x) {
  return x + __int_as_float(__builtin_amdgcn_update_dpp(
      0, __float_as_int(x), 0x141, 0xF, 0xF, true));
}
__device__ __forceinline__ float red8(float x) {
  x = dpp_xor1_add(x);
  x = dpp_xor2_add(x);
  x = dpp_xor7_add(x);
  return x;
}

// ---------------- prep: fold constants, softplus, emit SoA [j][i] f32 ----------------
__global__ __launch_bounds__(256) void prep_kernel(
    const float* __restrict__ sigma, const float* __restrict__ mu,
    const float* __restrict__ w,     const float* __restrict__ erev,
    const float* __restrict__ ss,    const float* __restrict__ smu,
    const float* __restrict__ sw,    const float* __restrict__ serev,
    const float* __restrict__ iw,    const float* __restrict__ ib,
    const float* __restrict__ gleak, const float* __restrict__ vleak,
    const float* __restrict__ cm,
    float* __restrict__ C2r, float* __restrict__ A2r, float* __restrict__ WEr,
    float* __restrict__ C2s, float* __restrict__ A2s, float* __restrict__ WEs,
    float* __restrict__ vecs)
{
  int gid = blockIdx.x * 256 + threadIdx.x;
  if (gid < 16384) {
    int i = gid >> 7, j = gid & 127;
    int idx = j * 128 + i;                    // transposed SoA [j][i]
    float a2 = sigma[gid] * LOG2E;
    float c2 = a2 * mu[gid];
    float sp = log1pf(expf(w[gid]));          // softplus(w) > 0
    float we = sp * erev[gid];                // erev = +-1
    C2r[idx] = c2; A2r[idx] = a2; WEr[idx] = we;
  } else if (gid < 32768) {
    int e = gid - 16384;
    int i = e >> 7, j = e & 127;
    int idx = j * 128 + i;
    float a2 = ss[e] * iw[i] * LOG2E;         // fold input_w
    float c2 = ss[e] * (smu[e] - ib[i]) * LOG2E; // fold input_b
    float sp = log1pf(expf(sw[e]));
    float we = sp * serev[e];
    C2s[idx] = c2; A2s[idx] = a2; WEs[idx] = we;
  } else if (gid < 32896) {
    int jj = gid - 32768;
    float gp = log1pf(expf(gleak[jj]));
    vecs[jj]       = log1pf(expf(cm[jj])) * 4.0f; // cm_t = softplus(cm)*ODE_UNFOLDS
    vecs[128 + jj] = gp;                          // gleak_p
    vecs[256 + jj] = gp * vleak[jj];              // gleak_p * vleak
  }
}

// ---------------- stage A: h = LN(x @ W^T + b), write bf16 (unchanged, known-good) ----------------
__global__ __launch_bounds__(256) void stage_a(
    const float* __restrict__ x, const float* __restrict__ W,
    const float* __restrict__ pb, const float* __restrict__ lg,
    const float* __restrict__ lb, uint4* __restrict__ hout)
{
  extern __shared__ char smem[];
  float* Wt = (float*)smem;            // [128][132] transposed W (k-major), padded
  float* xs = Wt + 128 * 132;          // [32][132]
  const int tid = threadIdx.x;

  #pragma unroll
  for (int ii = 0; ii < 16; ++ii) {
    int f = tid + (ii << 8);
    int jrow = f >> 5, kq = f & 31;
    float4 wv = ((const float4*)W)[f];
    float* wd = Wt + jrow;
    wd[(4 * kq + 0) * 132] = wv.x;
    wd[(4 * kq + 1) * 132] = wv.y;
    wd[(4 * kq + 2) * 132] = wv.z;
    wd[(4 * kq + 3) * 132] = wv.w;
  }
  const size_t R0 = (size_t)blockIdx.x << 5;   // 32 rows per block
  const float4* xg = (const float4*)(x + (R0 << 7));
  #pragma unroll
  for (int ii = 0; ii < 4; ++ii) {
    int f = tid + (ii << 8);
    int r = f >> 5, kq = f & 31;
    *(float4*)(xs + r * 132 + (kq << 2)) = xg[f];
  }
  __syncthreads();

  const int tr = tid >> 4, tc = tid & 15;
  const int r0 = tr << 1, j0 = tc << 3;
  float a0[8], a1[8];
  #pragma unroll
  for (int c = 0; c < 8; ++c) { a0[c] = 0.f; a1[c] = 0.f; }
  const float* xr0 = xs + r0 * 132;
  const float* xr1 = xs + (r0 + 1) * 132;
  const float* wc = Wt + j0;
  for (int k = 0; k < 128; k += 4) {
    float4 xa = *(const float4*)(xr0 + k);
    float4 xb = *(const float4*)(xr1 + k);
    #pragma unroll
    for (int s = 0; s < 4; ++s) {
      float4 w0 = *(const float4*)(wc + (k + s) * 132);
      float4 w1 = *(const float4*)(wc + (k + s) * 132 + 4);
      float xav = s == 0 ? xa.x : s == 1 ? xa.y : s == 2 ? xa.z : xa.w;
      float xbv = s == 0 ? xb.x : s == 1 ? xb.y : s == 2 ? xb.z : xb.w;
      a0[0] = fmaf(xav, w0.x, a0[0]); a0[1] = fmaf(xav, w0.y, a0[1]);
      a0[2] = fmaf(xav, w0.z, a0[2]); a0[3] = fmaf(xav, w0.w, a0[3]);
      a0[4] = fmaf(xav, w1.x, a0[4]); a0[5] = fmaf(xav, w1.y, a0[5]);
      a0[6] = fmaf(xav, w1.z, a0[6]); a0[7] = fmaf(xav, w1.w, a0[7]);
      a1[0] = fmaf(xbv, w0.x, a1[0]); a1[1] = fmaf(xbv, w0.y, a1[1]);
      a1[2] = fmaf(xbv, w0.z, a1[2]); a1[3] = fmaf(xbv, w0.w, a1[3]);
      a1[4] = fmaf(xbv, w1.x, a1[4]); a1[5] = fmaf(xbv, w1.y, a1[5]);
      a1[6] = fmaf(xbv, w1.z, a1[6]); a1[7] = fmaf(xbv, w1.w, a1[7]);
    }
  }
  float4 pb0 = *(const float4*)(pb + j0);
  float4 pb1 = *(const float4*)(pb + j0 + 4);
  a0[0] += pb0.x; a0[1] += pb0.y; a0[2] += pb0.z; a0[3] += pb0.w;
  a0[4] += pb1.x; a0[5] += pb1.y; a0[6] += pb1.z; a0[7] += pb1.w;
  a1[0] += pb0.x; a1[1] += pb0.y; a1[2] += pb0.z; a1[3] += pb0.w;
  a1[4] += pb1.x; a1[5] += pb1.y; a1[6] += pb1.z; a1[7] += pb1.w;
  float s0 = 0, q0 = 0, s1 = 0, q1 = 0;
  #pragma unroll
  for (int c = 0; c < 8; ++c) {
    s0 += a0[c]; q0 = fmaf(a0[c], a0[c], q0);
    s1 += a1[c]; q1 = fmaf(a1[c], a1[c], q1);
  }
  #pragma unroll
  for (int m = 1; m < 16; m <<= 1) {
    s0 += __shfl_xor(s0, m, 64); q0 += __shfl_xor(q0, m, 64);
    s1 += __shfl_xor(s1, m, 64); q1 += __shfl_xor(q1, m, 64);
  }
  float mu0 = s0 * (1.f / 128.f), mu1 = s1 * (1.f / 128.f);
  float rs0 = rsqrtf(fmaf(-mu0, mu0, q0 * (1.f / 128.f)) + 1e-5f);
  float rs1 = rsqrtf(fmaf(-mu1, mu1, q1 * (1.f / 128.f)) + 1e-5f);
  float4 g0 = *(const float4*)(lg + j0), g1 = *(const float4*)(lg + j0 + 4);
  float4 b0 = *(const float4*)(lb + j0), b1 = *(const float4*)(lb + j0 + 4);
  float n0[8], n1[8];
  const float* gv = (const float*)&g0; const float* bv = (const float*)&b0;
  #pragma unroll
  for (int c = 0; c < 4; ++c) {
    n0[c] = fmaf((a0[c] - mu0) * rs0, gv[c], bv[c]);
    n1[c] = fmaf((a1[c] - mu1) * rs1, gv[c], bv[c]);
  }
  const float* gv1 = (const float*)&g1; const float* bv1 = (const float*)&b1;
  #pragma unroll
  for (int c = 0; c < 4; ++c) {
    n0[4 + c] = fmaf((a0[4 + c] - mu0) * rs0, gv1[c], bv1[c]);
    n1[4 + c] = fmaf((a1[4 + c] - mu1) * rs1, gv1[c], bv1[c]);
  }
  uint4 o0, o1;
  o0.x = pk2(n0[0], n0[1]); o0.y = pk2(n0[2], n0[3]);
  o0.z = pk2(n0[4], n0[5]); o0.w = pk2(n0[6], n0[7]);
  o1.x = pk2(n1[0], n1[1]); o1.y = pk2(n1[2], n1[3]);
  o1.z = pk2(n1[4], n1[5]); o1.w = pk2(n1[6], n1[7]);
  hout[(R0 + r0) * 16 + tc] = o0;
  hout[(R0 + r0 + 1) * 16 + tc] = o1;
}

// ---------------- stage B: sensory terms — pinned reg params, wide-ILP, DPP reduce ----------------
__global__ __launch_bounds__(1024, 4) void sensory_kernel(
    const float* __restrict__ C2, const float* __restrict__ A2,
    const float* __restrict__ WE,
    const uint4* __restrict__ hbf, unsigned* __restrict__ ndg)
{
  const int tid = threadIdx.x;
  const int lane = tid & 63, wv = tid >> 6;
  const int iq = lane & 7, jj = lane >> 3;
  const int j = wv * 8 + jj;

  float c2s[16], a2s[16], wes[16];
  const int pbase = j * 128 + iq * 16;
  #pragma unroll
  for (int k = 0; k < 16; ++k) {
    c2s[k] = pinned_load(C2 + pbase + k);
    a2s[k] = pinned_load(A2 + pbase + k);
    wes[k] = pinned_load(WE + pbase + k);
  }

  const int p0 = blockIdx.x << 9;        // 512 pairs per block
  uint4 hc0 = hbf[((size_t)p0 << 4) + iq * 2];
  uint4 hc1 = hbf[((size_t)p0 << 4) + iq * 2 + 1];

  for (int q = 0; q < 512; ++q) {
    const int p = p0 + q;
    const int pn = p0 + (q + 1 < 512 ? q + 1 : q);
    uint4 hn0 = hbf[((size_t)pn << 4) + iq * 2];
    uint4 hn1 = hbf[((size_t)pn << 4) + iq * 2 + 1];

    float hv[16];
    hv[0] = bl16(hc0.x);  hv[1] = bh16(hc0.x);
    hv[2] = bl16(hc0.y);  hv[3] = bh16(hc0.y);
    hv[4] = bl16(hc0.z);  hv[5] = bh16(hc0.z);
    hv[6] = bl16(hc0.w);  hv[7] = bh16(hc0.w);
    hv[8] = bl16(hc1.x);  hv[9] = bh16(hc1.x);
    hv[10] = bl16(hc1.y); hv[11] = bh16(hc1.y);
    hv[12] = bl16(hc1.z); hv[13] = bh16(hc1.z);
    hv[14] = bl16(hc1.w); hv[15] = bh16(hc1.w);

    // wide-ILP: all 16 q's, then all 16 rcp's, then 4 independent acc chains
    float qa[16];
    #pragma unroll
    for (int k = 0; k < 16; ++k)
      qa[k] = 1.0f + __builtin_amdgcn_exp2f(fmaf(-a2s[k], hv[k], c2s[k]));
    float ra[16];
    #pragma unroll
    for (int k = 0; k < 16; ++k)
      ra[k] = __builtin_amdgcn_rcpf(qa[k]);
    float an0 = 0.f, an1 = 0.f, an2 = 0.f, an3 = 0.f;
    float ad0 = 0.f, ad1 = 0.f, ad2 = 0.f, ad3 = 0.f;
    #pragma unroll
    for (int c = 0; c < 4; ++c) {
      an0 = fmaf(wes[4*c+0], ra[4*c+0], an0); ad0 = fmaf(fabsf(wes[4*c+0]), ra[4*c+0], ad0);
      an1 = fmaf(wes[4*c+1], ra[4*c+1], an1); ad1 = fmaf(fabsf(wes[4*c+1]), ra[4*c+1], ad1);
      an2 = fmaf(wes[4*c+2], ra[4*c+2], an2); ad2 = fmaf(fabsf(wes[4*c+2]), ra[4*c+2], ad2);
      an3 = fmaf(wes[4*c+3], ra[4*c+3], an3); ad3 = fmaf(fabsf(wes[4*c+3]), ra[4*c+3], ad3);
    }
    float an = (an0 + an1) + (an2 + an3);
    float ad = (ad0 + ad1) + (ad2 + ad3);

    an = red8(an);
    ad = red8(ad);
    if (iq == 0) ndg[((size_t)p << 7) + j] = pk2(an, ad);
    hc0 = hn0; hc1 = hn1;
  }
}

// ---------------- stage C: sequential LTC scan — pinned params, wide-ILP, stride-36 v ----------------
__global__ __launch_bounds__(1024, 4) void ltc_scan(
    const float* __restrict__ C2, const float* __restrict__ A2,
    const float* __restrict__ WE,
    const float* __restrict__ vecs, const unsigned* __restrict__ ndg,
    const float* __restrict__ ow, const float* __restrict__ ob,
    const float* __restrict__ lng, const float* __restrict__ lnb,
    const float* __restrict__ hW, const float* __restrict__ hb,
    float* __restrict__ out)
{
  __shared__ float vbuf[2][8 * 36];
  __shared__ float ov[128], lnv[128], mv[2];

  const int tid = threadIdx.x;
  const int lane = tid & 63, wv = tid >> 6;
  const int iq = lane & 7, jj = lane >> 3;
  const int j = wv * 8 + jj;
  const int b = blockIdx.x;
  const int vpos_j = ((j >> 4) * 36) + (j & 15);

  float c2s[16], a2s[16], wes[16];
  const int pbase = j * 128 + iq * 16;
  #pragma unroll
  for (int k = 0; k < 16; ++k) {
    c2s[k] = pinned_load(C2 + pbase + k);
    a2s[k] = pinned_load(A2 + pbase + k);
    wes[k] = pinned_load(WE + pbase + k);
  }
  const float cmtj = vecs[j];
  const float gdj  = vecs[128 + j];
  const float gnj  = vecs[256 + j];
  const float cgd  = cmtj + gdj + 1e-8f;      // folded denominator constant
  float vj = 0.f;
  if (tid < 128) vbuf[0][((tid >> 4) * 36) + (tid & 15)] = 0.f;
  __syncthreads();

  const size_t ndbase = ((size_t)b << 17) + j;   // b*1024*128 + j
  unsigned ndc = ndg[ndbase];                    // t = 0 sensory terms
  for (int t = 0; t < 1024; ++t) {
    const int tn = (t + 1 < 1024) ? t + 1 : 1023;
    unsigned ndn = ndg[ndbase + ((size_t)tn << 7)];   // prefetch next t (stays in flight)
    const float snum = bl16(ndc), sden = bh16(ndc);
    #pragma unroll
    for (int u = 0; u < 4; ++u) {
      const float* vc = vbuf[u & 1] + iq * 36;
      // wide-ILP: 16 q's -> 16 rcp's -> 4 independent acc chains -> tree
      float qa[16];
      #pragma unroll
      for (int c = 0; c < 4; ++c) {
        float4 vv = *(const float4*)(vc + 4 * c);
        qa[4*c+0] = 1.0f + __builtin_amdgcn_exp2f(fmaf(-a2s[4*c+0], vv.x, c2s[4*c+0]));
        qa[4*c+1] = 1.0f + __builtin_amdgcn_exp2f(fmaf(-a2s[4*c+1], vv.y, c2s[4*c+1]));
        qa[4*c+2] = 1.0f + __builtin_amdgcn_exp2f(fmaf(-a2s[4*c+2], vv.z, c2s[4*c+2]));
        qa[4*c+3] = 1.0f + __builtin_amdgcn_exp2f(fmaf(-a2s[4*c+3], vv.w, c2s[4*c+3]));
      }
      float ra[16];
      #pragma unroll
      for (int k = 0; k < 16; ++k)
        ra[k] = __builtin_amdgcn_rcpf(qa[k]);
      float an0 = 0.f, an1 = 0.f, an2 = 0.f, an3 = 0.f;
      float ad0 = 0.f, ad1 = 0.f, ad2 = 0.f, ad3 = 0.f;
      #pragma unroll
      for (int c = 0; c < 4; ++c) {
        an0 = fmaf(wes[4*c+0], ra[4*c+0], an0); ad0 = fmaf(fabsf(wes[4*c+0]), ra[4*c+0], ad0);
        an1 = fmaf(wes[4*c+1], ra[4*c+1], an1); ad1 = fmaf(fabsf(wes[4*c+1]), ra[4*c+1], ad1);
        an2 = fmaf(wes[4*c+2], ra[4*c+2], an2); ad2 = fmaf(fabsf(wes[4*c+2]), ra[4*c+2], ad2);
        an3 = fmaf(wes[4*c+3], ra[4*c+3], an3); ad3 = fmaf(fabsf(wes[4*c+3]), ra[4*c+3], ad3);
      }
      float an = red8((an0 + an1) + (an2 + an3));
      float ad = red8((ad0 + ad1) + (ad2 + ad3));
      // all lanes compute vnew for their j (identical across iq dups) -> vj stays in reg
      float num = an + snum;
      float den = ad + sden;
      float vnew = (fmaf(cmtj, vj, gnj) + num) *
                   __builtin_amdgcn_rcpf(cgd + den);
      if (iq == 0) vbuf[(u & 1) ^ 1][vpos_j] = vnew;
      vj = vnew;
      lds_barrier();               // LDS-visibility only; no vmcnt drain
    }
    ndc = ndn;
  }

  // epilogue: out affine -> layernorm -> head matmul (final v is in vbuf[0], padded layout)
  __syncthreads();
  if (tid < 128)
    ov[tid] = fmaf(vbuf[0][((tid >> 4) * 36) + (tid & 15)], ow[tid], ob[tid]);
  __syncthreads();
  if (tid < 64) {
    float a = ov[tid], c = ov[tid + 64];
    float s = a + c, s2 = fmaf(a, a, c * c);
    #pragma unroll
    for (int m = 1; m < 64; m <<= 1) {
      s += __shfl_xor(s, m, 64);
      s2 += __shfl_xor(s2, m, 64);
    }
    if (tid == 0) {
      float mean = s * (1.f / 128.f);
      float var = s2 * (1.f / 128.f) - mean * mean;
      mv[0] = mean;
      mv[1] = rsqrtf(var + 1e-5f);
    }
  }
  __syncthreads();
  if (tid < 128) lnv[tid] = fmaf((ov[tid] - mv[0]) * mv[1], lng[tid], lnb[tid]);
  __syncthreads();
  if (tid < 15) {
    float acc = hb[tid];
    const float* wr = hW + tid * 128;
    #pragma unroll
    for (int k = 0; k < 128; k += 4) {
      float4 wvv = *(const float4*)(wr + k);
      acc = fmaf(wvv.x, lnv[k], acc);
      acc = fmaf(wvv.y, lnv[k + 1], acc);
      acc = fmaf(wvv.z, lnv[k + 2], acc);
      acc = fmaf(wvv.w, lnv[k + 3], acc);
    }
    out[b * 15 + tid] = acc;
  }
}

// ---------------- launch ----------------
extern "C" void kernel_launch(void* const* d_in, const int* in_sizes, int n_in,
                              void* d_out, int out_size, void* d_ws, size_t ws_size,
                              hipStream_t stream) {
  const float* x      = (const float*)d_in[0];
  const float* pre_W  = (const float*)d_in[1];
  const float* pre_b  = (const float*)d_in[2];
  const float* plg    = (const float*)d_in[3];
  const float* plb    = (const float*)d_in[4];
  const float* gleak  = (const float*)d_in[5];
  const float* vleak  = (const float*)d_in[6];
  const float* cm     = (const float*)d_in[7];
  const float* sigma  = (const float*)d_in[8];
  const float* mu     = (const float*)d_in[9];
  const float* w      = (const float*)d_in[10];
  const float* erev   = (const float*)d_in[11];
  const float* ss     = (const float*)d_in[12];
  const float* smu    = (const float*)d_in[13];
  const float* sw     = (const float*)d_in[14];
  const float* serev  = (const float*)d_in[15];
  const float* iw     = (const float*)d_in[16];
  const float* ib     = (const float*)d_in[17];
  const float* ow     = (const float*)d_in[18];
  const float* ob     = (const float*)d_in[19];
  const float* lng    = (const float*)d_in[20];
  const float* lnb    = (const float*)d_in[21];
  const float* hW     = (const float*)d_in[22];
  const float* hb     = (const float*)d_in[23];
  float* out = (float*)d_out;

  char* ws = (char*)d_ws;
  float* C2r = (float*)(ws + 0 * 65536);
  float* A2r = (float*)(ws + 1 * 65536);
  float* WEr = (float*)(ws + 2 * 65536);
  float* C2s = (float*)(ws + 3 * 65536);
  float* A2s = (float*)(ws + 4 * 65536);
  float* WEs = (float*)(ws + 5 * 65536);
  float* vecs   = (float*)(ws + 6 * 65536);               // 1.5 KB
  uint4* hbf    = (uint4*)(ws + 1048576);                 // 32 MB (bf16 h_ln)
  unsigned* ndg = (unsigned*)(ws + 1048576 + 33554432);   // 64 MB (bf16 num|den)

  prep_kernel<<<129, 256, 0, stream>>>(sigma, mu, w, erev, ss, smu, sw, serev,
                                       iw, ib, gleak, vleak, cm,
                                       C2r, A2r, WEr, C2s, A2s, WEs, vecs);
  stage_a<<<4096, 256, 84480, stream>>>(x, pre_W, pre_b, plg, plb, hbf);
  sensory_kernel<<<256, 1024, 0, stream>>>(C2s, A2s, WEs, hbf, ndg);
  ltc_scan<<<128, 1024, 0, stream>>>(C2r, A2r, WEr, vecs, ndg,
                                     ow, ob, lng, lnb, hW, hb, out);
}

// Round 10
// 5178.849 us; speedup vs baseline: 1.0067x; 1.0067x over previous
//
#include <hip/hip_runtime.h>

#define LOG2E 1.4426950408889634f

__device__ __forceinline__ unsigned short f2bf(float f) {
  unsigned u = __float_as_uint(f);
  u += 0x7FFFu + ((u >> 16) & 1u);            // round-to-nearest-even
  return (unsigned short)(u >> 16);
}
__device__ __forceinline__ unsigned pk2(float a, float b) {
  return (unsigned)f2bf(a) | ((unsigned)f2bf(b) << 16);
}
__device__ __forceinline__ float bl16(unsigned u) { return __uint_as_float(u << 16); }
__device__ __forceinline__ float bh16(unsigned u) { return __uint_as_float(u & 0xFFFF0000u); }

// LDS-visibility barrier WITHOUT the vmcnt(0) drain __syncthreads would emit.
__device__ __forceinline__ void lds_barrier() {
  asm volatile("s_waitcnt lgkmcnt(0)" ::: "memory");
  __builtin_amdgcn_s_barrier();
}

// DPP cross-lane adds (VALU pipe): reduce over 8 consecutive lanes.
__device__ __forceinline__ float dpp_xor1_add(float x) {
  return x + __int_as_float(__builtin_amdgcn_update_dpp(
      0, __float_as_int(x), 0xB1, 0xF, 0xF, true));
}
__device__ __forceinline__ float dpp_xor2_add(float x) {
  return x + __int_as_float(__builtin_amdgcn_update_dpp(
      0, __float_as_int(x), 0x4E, 0xF, 0xF, true));
}
__device__ __forceinline__ float dpp_xor7_add(float x) {
  return x + __int_as_float(__builtin_amdgcn_update_dpp(
      0, __float_as_int(x), 0x141, 0xF, 0xF, true));
}
__device__ __forceinline__ float red8(float x) {
  x = dpp_xor1_add(x);
  x = dpp_xor2_add(x);
  x = dpp_xor7_add(x);
  return x;
}

// ---------------- prep: fold constants, softplus, emit SoA [j][i] f32 ----------------
__global__ __launch_bounds__(256) void prep_kernel(
    const float* __restrict__ sigma, const float* __restrict__ mu,
    const float* __restrict__ w,     const float* __restrict__ erev,
    const float* __restrict__ ss,    const float* __restrict__ smu,
    const float* __restrict__ sw,    const float* __restrict__ serev,
    const float* __restrict__ iw,    const float* __restrict__ ib,
    const float* __restrict__ gleak, const float* __restrict__ vleak,
    const float* __restrict__ cm,
    float* __restrict__ C2r, float* __restrict__ A2r, float* __restrict__ WEr,
    float* __restrict__ C2s, float* __restrict__ A2s, float* __restrict__ WEs,
    float* __restrict__ vecs)
{
  int gid = blockIdx.x * 256 + threadIdx.x;
  if (gid < 16384) {
    int i = gid >> 7, j = gid & 127;
    int idx = j * 128 + i;                    // transposed SoA [j][i]
    float a2 = sigma[gid] * LOG2E;
    float c2 = a2 * mu[gid];
    float sp = log1pf(expf(w[gid]));          // softplus(w) > 0
    float we = sp * erev[gid];                // erev = +-1
    C2r[idx] = c2; A2r[idx] = a2; WEr[idx] = we;
  } else if (gid < 32768) {
    int e = gid - 16384;
    int i = e >> 7, j = e & 127;
    int idx = j * 128 + i;
    float a2 = ss[e] * iw[i] * LOG2E;         // fold input_w
    float c2 = ss[e] * (smu[e] - ib[i]) * LOG2E; // fold input_b
    float sp = log1pf(expf(sw[e]));
    float we = sp * serev[e];
    C2s[idx] = c2; A2s[idx] = a2; WEs[idx] = we;
  } else if (gid < 32896) {
    int jj = gid - 32768;
    float gp = log1pf(expf(gleak[jj]));
    vecs[jj]       = log1pf(expf(cm[jj])) * 4.0f; // cm_t = softplus(cm)*ODE_UNFOLDS
    vecs[128 + jj] = gp;                          // gleak_p
    vecs[256 + jj] = gp * vleak[jj];              // gleak_p * vleak
  }
}

// ---------------- stage A: h = LN(x @ W^T + b), write bf16 (unchanged, known-good) ----------------
__global__ __launch_bounds__(256) void stage_a(
    const float* __restrict__ x, const float* __restrict__ W,
    const float* __restrict__ pb, const float* __restrict__ lg,
    const float* __restrict__ lb, uint4* __restrict__ hout)
{
  extern __shared__ char smem[];
  float* Wt = (float*)smem;            // [128][132] transposed W (k-major), padded
  float* xs = Wt + 128 * 132;          // [32][132]
  const int tid = threadIdx.x;

  #pragma unroll
  for (int ii = 0; ii < 16; ++ii) {
    int f = tid + (ii << 8);
    int jrow = f >> 5, kq = f & 31;
    float4 wv = ((const float4*)W)[f];
    float* wd = Wt + jrow;
    wd[(4 * kq + 0) * 132] = wv.x;
    wd[(4 * kq + 1) * 132] = wv.y;
    wd[(4 * kq + 2) * 132] = wv.z;
    wd[(4 * kq + 3) * 132] = wv.w;
  }
  const size_t R0 = (size_t)blockIdx.x << 5;   // 32 rows per block
  const float4* xg = (const float4*)(x + (R0 << 7));
  #pragma unroll
  for (int ii = 0; ii < 4; ++ii) {
    int f = tid + (ii << 8);
    int r = f >> 5, kq = f & 31;
    *(float4*)(xs + r * 132 + (kq << 2)) = xg[f];
  }
  __syncthreads();

  const int tr = tid >> 4, tc = tid & 15;
  const int r0 = tr << 1, j0 = tc << 3;
  float a0[8], a1[8];
  #pragma unroll
  for (int c = 0; c < 8; ++c) { a0[c] = 0.f; a1[c] = 0.f; }
  const float* xr0 = xs + r0 * 132;
  const float* xr1 = xs + (r0 + 1) * 132;
  const float* wc = Wt + j0;
  for (int k = 0; k < 128; k += 4) {
    float4 xa = *(const float4*)(xr0 + k);
    float4 xb = *(const float4*)(xr1 + k);
    #pragma unroll
    for (int s = 0; s < 4; ++s) {
      float4 w0 = *(const float4*)(wc + (k + s) * 132);
      float4 w1 = *(const float4*)(wc + (k + s) * 132 + 4);
      float xav = s == 0 ? xa.x : s == 1 ? xa.y : s == 2 ? xa.z : xa.w;
      float xbv = s == 0 ? xb.x : s == 1 ? xb.y : s == 2 ? xb.z : xb.w;
      a0[0] = fmaf(xav, w0.x, a0[0]); a0[1] = fmaf(xav, w0.y, a0[1]);
      a0[2] = fmaf(xav, w0.z, a0[2]); a0[3] = fmaf(xav, w0.w, a0[3]);
      a0[4] = fmaf(xav, w1.x, a0[4]); a0[5] = fmaf(xav, w1.y, a0[5]);
      a0[6] = fmaf(xav, w1.z, a0[6]); a0[7] = fmaf(xav, w1.w, a0[7]);
      a1[0] = fmaf(xbv, w0.x, a1[0]); a1[1] = fmaf(xbv, w0.y, a1[1]);
      a1[2] = fmaf(xbv, w0.z, a1[2]); a1[3] = fmaf(xbv, w0.w, a1[3]);
      a1[4] = fmaf(xbv, w1.x, a1[4]); a1[5] = fmaf(xbv, w1.y, a1[5]);
      a1[6] = fmaf(xbv, w1.z, a1[6]); a1[7] = fmaf(xbv, w1.w, a1[7]);
    }
  }
  float4 pb0 = *(const float4*)(pb + j0);
  float4 pb1 = *(const float4*)(pb + j0 + 4);
  a0[0] += pb0.x; a0[1] += pb0.y; a0[2] += pb0.z; a0[3] += pb0.w;
  a0[4] += pb1.x; a0[5] += pb1.y; a0[6] += pb1.z; a0[7] += pb1.w;
  a1[0] += pb0.x; a1[1] += pb0.y; a1[2] += pb0.z; a1[3] += pb0.w;
  a1[4] += pb1.x; a1[5] += pb1.y; a1[6] += pb1.z; a1[7] += pb1.w;
  float s0 = 0, q0 = 0, s1 = 0, q1 = 0;
  #pragma unroll
  for (int c = 0; c < 8; ++c) {
    s0 += a0[c]; q0 = fmaf(a0[c], a0[c], q0);
    s1 += a1[c]; q1 = fmaf(a1[c], a1[c], q1);
  }
  #pragma unroll
  for (int m = 1; m < 16; m <<= 1) {
    s0 += __shfl_xor(s0, m, 64); q0 += __shfl_xor(q0, m, 64);
    s1 += __shfl_xor(s1, m, 64); q1 += __shfl_xor(q1, m, 64);
  }
  float mu0 = s0 * (1.f / 128.f), mu1 = s1 * (1.f / 128.f);
  float rs0 = rsqrtf(fmaf(-mu0, mu0, q0 * (1.f / 128.f)) + 1e-5f);
  float rs1 = rsqrtf(fmaf(-mu1, mu1, q1 * (1.f / 128.f)) + 1e-5f);
  float4 g0 = *(const float4*)(lg + j0), g1 = *(const float4*)(lg + j0 + 4);
  float4 b0 = *(const float4*)(lb + j0), b1 = *(const float4*)(lb + j0 + 4);
  float n0[8], n1[8];
  const float* gv = (const float*)&g0; const float* bv = (const float*)&b0;
  #pragma unroll
  for (int c = 0; c < 4; ++c) {
    n0[c] = fmaf((a0[c] - mu0) * rs0, gv[c], bv[c]);
    n1[c] = fmaf((a1[c] - mu1) * rs1, gv[c], bv[c]);
  }
  const float* gv1 = (const float*)&g1; const float* bv1 = (const float*)&b1;
  #pragma unroll
  for (int c = 0; c < 4; ++c) {
    n0[4 + c] = fmaf((a0[4 + c] - mu0) * rs0, gv1[c], bv1[c]);
    n1[4 + c] = fmaf((a1[4 + c] - mu1) * rs1, gv1[c], bv1[c]);
  }
  uint4 o0, o1;
  o0.x = pk2(n0[0], n0[1]); o0.y = pk2(n0[2], n0[3]);
  o0.z = pk2(n0[4], n0[5]); o0.w = pk2(n0[6], n0[7]);
  o1.x = pk2(n1[0], n1[1]); o1.y = pk2(n1[2], n1[3]);
  o1.z = pk2(n1[4], n1[5]); o1.w = pk2(n1[6], n1[7]);
  hout[(R0 + r0) * 16 + tc] = o0;
  hout[(R0 + r0 + 1) * 16 + tc] = o1;
}

// ---------------- stage B: sensory terms — reg params, wide-ILP, DPP reduce ----------------
// amdgpu_waves_per_eu(4,4): exactly 16 waves/CU (1 block) -> VGPR budget 128,
// scheduler stops minimizing registers and keeps params + wide arrays live.
__global__ __attribute__((amdgpu_flat_work_group_size(1024, 1024)))
__attribute__((amdgpu_waves_per_eu(4, 4))) void sensory_kernel(
    const float* __restrict__ C2, const float* __restrict__ A2,
    const float* __restrict__ WE,
    const uint4* __restrict__ hbf, unsigned* __restrict__ ndg)
{
  const int tid = threadIdx.x;
  const int lane = tid & 63, wv = tid >> 6;
  const int iq = lane & 7, jj = lane >> 3;
  const int j = wv * 8 + jj;

  float c2s[16], a2s[16], wes[16];
  const int pbase = j * 128 + iq * 16;
  #pragma unroll
  for (int k = 0; k < 16; ++k) {
    c2s[k] = C2[pbase + k];
    a2s[k] = A2[pbase + k];
    wes[k] = WE[pbase + k];
  }

  const int p0 = blockIdx.x << 9;        // 512 pairs per block
  uint4 hc0 = hbf[((size_t)p0 << 4) + iq * 2];
  uint4 hc1 = hbf[((size_t)p0 << 4) + iq * 2 + 1];

  for (int q = 0; q < 512; ++q) {
    const int p = p0 + q;
    const int pn = p0 + (q + 1 < 512 ? q + 1 : q);
    uint4 hn0 = hbf[((size_t)pn << 4) + iq * 2];
    uint4 hn1 = hbf[((size_t)pn << 4) + iq * 2 + 1];

    float hv[16];
    hv[0] = bl16(hc0.x);  hv[1] = bh16(hc0.x);
    hv[2] = bl16(hc0.y);  hv[3] = bh16(hc0.y);
    hv[4] = bl16(hc0.z);  hv[5] = bh16(hc0.z);
    hv[6] = bl16(hc0.w);  hv[7] = bh16(hc0.w);
    hv[8] = bl16(hc1.x);  hv[9] = bh16(hc1.x);
    hv[10] = bl16(hc1.y); hv[11] = bh16(hc1.y);
    hv[12] = bl16(hc1.z); hv[13] = bh16(hc1.z);
    hv[14] = bl16(hc1.w); hv[15] = bh16(hc1.w);

    // wide-ILP: all 16 q's, then all 16 rcp's, then 4 independent acc chains
    float qa[16];
    #pragma unroll
    for (int k = 0; k < 16; ++k)
      qa[k] = 1.0f + __builtin_amdgcn_exp2f(fmaf(-a2s[k], hv[k], c2s[k]));
    float ra[16];
    #pragma unroll
    for (int k = 0; k < 16; ++k)
      ra[k] = __builtin_amdgcn_rcpf(qa[k]);
    float an0 = 0.f, an1 = 0.f, an2 = 0.f, an3 = 0.f;
    float ad0 = 0.f, ad1 = 0.f, ad2 = 0.f, ad3 = 0.f;
    #pragma unroll
    for (int c = 0; c < 4; ++c) {
      an0 = fmaf(wes[4*c+0], ra[4*c+0], an0); ad0 = fmaf(fabsf(wes[4*c+0]), ra[4*c+0], ad0);
      an1 = fmaf(wes[4*c+1], ra[4*c+1], an1); ad1 = fmaf(fabsf(wes[4*c+1]), ra[4*c+1], ad1);
      an2 = fmaf(wes[4*c+2], ra[4*c+2], an2); ad2 = fmaf(fabsf(wes[4*c+2]), ra[4*c+2], ad2);
      an3 = fmaf(wes[4*c+3], ra[4*c+3], an3); ad3 = fmaf(fabsf(wes[4*c+3]), ra[4*c+3], ad3);
    }
    float an = (an0 + an1) + (an2 + an3);
    float ad = (ad0 + ad1) + (ad2 + ad3);

    an = red8(an);
    ad = red8(ad);
    if (iq == 0) ndg[((size_t)p << 7) + j] = pk2(an, ad);
    hc0 = hn0; hc1 = hn1;
  }
}

// ---------------- stage C: sequential LTC scan — wide-ILP + forced 4 waves/EU ----------------
__global__ __attribute__((amdgpu_flat_work_group_size(1024, 1024)))
__attribute__((amdgpu_waves_per_eu(4, 4))) void ltc_scan(
    const float* __restrict__ C2, const float* __restrict__ A2,
    const float* __restrict__ WE,
    const float* __restrict__ vecs, const unsigned* __restrict__ ndg,
    const float* __restrict__ ow, const float* __restrict__ ob,
    const float* __restrict__ lng, const float* __restrict__ lnb,
    const float* __restrict__ hW, const float* __restrict__ hb,
    float* __restrict__ out)
{
  __shared__ float vbuf[2][8 * 36];
  __shared__ float ov[128], lnv[128], mv[2];

  const int tid = threadIdx.x;
  const int lane = tid & 63, wv = tid >> 6;
  const int iq = lane & 7, jj = lane >> 3;
  const int j = wv * 8 + jj;
  const int b = blockIdx.x;
  const int vpos_j = ((j >> 4) * 36) + (j & 15);

  float c2s[16], a2s[16], wes[16];
  const int pbase = j * 128 + iq * 16;
  #pragma unroll
  for (int k = 0; k < 16; ++k) {
    c2s[k] = C2[pbase + k];
    a2s[k] = A2[pbase + k];
    wes[k] = WE[pbase + k];
  }
  const float cmtj = vecs[j];
  const float gdj  = vecs[128 + j];
  const float gnj  = vecs[256 + j];
  const float cgd  = cmtj + gdj + 1e-8f;      // folded denominator constant
  float vj = 0.f;
  if (tid < 128) vbuf[0][((tid >> 4) * 36) + (tid & 15)] = 0.f;
  __syncthreads();

  const size_t ndbase = ((size_t)b << 17) + j;   // b*1024*128 + j
  unsigned ndc = ndg[ndbase];                    // t = 0 sensory terms
  for (int t = 0; t < 1024; ++t) {
    const int tn = (t + 1 < 1024) ? t + 1 : 1023;
    unsigned ndn = ndg[ndbase + ((size_t)tn << 7)];   // prefetch next t (stays in flight)
    const float snum = bl16(ndc), sden = bh16(ndc);
    #pragma unroll
    for (int u = 0; u < 4; ++u) {
      const float* vc = vbuf[u & 1] + iq * 36;
      // wide-ILP: 16 q's -> 16 rcp's -> 4 independent acc chains -> tree
      float qa[16];
      #pragma unroll
      for (int c = 0; c < 4; ++c) {
        float4 vv = *(const float4*)(vc + 4 * c);
        qa[4*c+0] = 1.0f + __builtin_amdgcn_exp2f(fmaf(-a2s[4*c+0], vv.x, c2s[4*c+0]));
        qa[4*c+1] = 1.0f + __builtin_amdgcn_exp2f(fmaf(-a2s[4*c+1], vv.y, c2s[4*c+1]));
        qa[4*c+2] = 1.0f + __builtin_amdgcn_exp2f(fmaf(-a2s[4*c+2], vv.z, c2s[4*c+2]));
        qa[4*c+3] = 1.0f + __builtin_amdgcn_exp2f(fmaf(-a2s[4*c+3], vv.w, c2s[4*c+3]));
      }
      float ra[16];
      #pragma unroll
      for (int k = 0; k < 16; ++k)
        ra[k] = __builtin_amdgcn_rcpf(qa[k]);
      float an0 = 0.f, an1 = 0.f, an2 = 0.f, an3 = 0.f;
      float ad0 = 0.f, ad1 = 0.f, ad2 = 0.f, ad3 = 0.f;
      #pragma unroll
      for (int c = 0; c < 4; ++c) {
        an0 = fmaf(wes[4*c+0], ra[4*c+0], an0); ad0 = fmaf(fabsf(wes[4*c+0]), ra[4*c+0], ad0);
        an1 = fmaf(wes[4*c+1], ra[4*c+1], an1); ad1 = fmaf(fabsf(wes[4*c+1]), ra[4*c+1], ad1);
        an2 = fmaf(wes[4*c+2], ra[4*c+2], an2); ad2 = fmaf(fabsf(wes[4*c+2]), ra[4*c+2], ad2);
        an3 = fmaf(wes[4*c+3], ra[4*c+3], an3); ad3 = fmaf(fabsf(wes[4*c+3]), ra[4*c+3], ad3);
      }
      float an = red8((an0 + an1) + (an2 + an3));
      float ad = red8((ad0 + ad1) + (ad2 + ad3));
      // all lanes compute vnew for their j (identical across iq dups) -> vj stays in reg
      float num = an + snum;
      float den = ad + sden;
      float vnew = (fmaf(cmtj, vj, gnj) + num) *
                   __builtin_amdgcn_rcpf(cgd + den);
      if (iq == 0) vbuf[(u & 1) ^ 1][vpos_j] = vnew;
      vj = vnew;
      lds_barrier();               // LDS-visibility only; no vmcnt drain
    }
    ndc = ndn;
  }

  // epilogue: out affine -> layernorm -> head matmul (final v is in vbuf[0], padded layout)
  __syncthreads();
  if (tid < 128)
    ov[tid] = fmaf(vbuf[0][((tid >> 4) * 36) + (tid & 15)], ow[tid], ob[tid]);
  __syncthreads();
  if (tid < 64) {
    float a = ov[tid], c = ov[tid + 64];
    float s = a + c, s2 = fmaf(a, a, c * c);
    #pragma unroll
    for (int m = 1; m < 64; m <<= 1) {
      s += __shfl_xor(s, m, 64);
      s2 += __shfl_xor(s2, m, 64);
    }
    if (tid == 0) {
      float mean = s * (1.f / 128.f);
      float var = s2 * (1.f / 128.f) - mean * mean;
      mv[0] = mean;
      mv[1] = rsqrtf(var + 1e-5f);
    }
  }
  __syncthreads();
  if (tid < 128) lnv[tid] = fmaf((ov[tid] - mv[0]) * mv[1], lng[tid], lnb[tid]);
  __syncthreads();
  if (tid < 15) {
    float acc = hb[tid];
    const float* wr = hW + tid * 128;
    #pragma unroll
    for (int k = 0; k < 128; k += 4) {
      float4 wvv = *(const float4*)(wr + k);
      acc = fmaf(wvv.x, lnv[k], acc);
      acc = fmaf(wvv.y, lnv[k + 1], acc);
      acc = fmaf(wvv.z, lnv[k + 2], acc);
      acc = fmaf(wvv.w, lnv[k + 3], acc);
    }
    out[b * 15 + tid] = acc;
  }
}

// ---------------- launch ----------------
extern "C" void kernel_launch(void* const* d_in, const int* in_sizes, int n_in,
                              void* d_out, int out_size, void* d_ws, size_t ws_size,
                              hipStream_t stream) {
  const float* x      = (const float*)d_in[0];
  const float* pre_W  = (const float*)d_in[1];
  const float* pre_b  = (const float*)d_in[2];
  const float* plg    = (const float*)d_in[3];
  const float* plb    = (const float*)d_in[4];
  const float* gleak  = (const float*)d_in[5];
  const float* vleak  = (const float*)d_in[6];
  const float* cm     = (const float*)d_in[7];
  const float* sigma  = (const float*)d_in[8];
  const float* mu     = (const float*)d_in[9];
  const float* w      = (const float*)d_in[10];
  const float* erev   = (const float*)d_in[11];
  const float* ss     = (const float*)d_in[12];
  const float* smu    = (const float*)d_in[13];
  const float* sw     = (const float*)d_in[14];
  const float* serev  = (const float*)d_in[15];
  const float* iw     = (const float*)d_in[16];
  const float* ib     = (const float*)d_in[17];
  const float* ow     = (const float*)d_in[18];
  const float* ob     = (const float*)d_in[19];
  const float* lng    = (const float*)d_in[20];
  const float* lnb    = (const float*)d_in[21];
  const float* hW     = (const float*)d_in[22];
  const float* hb     = (const float*)d_in[23];
  float* out = (float*)d_out;

  char* ws = (char*)d_ws;
  float* C2r = (float*)(ws + 0 * 65536);
  float* A2r = (float*)(ws + 1 * 65536);
  float* WEr = (float*)(ws + 2 * 65536);
  float* C2s = (float*)(ws + 3 * 65536);
  float* A2s = (float*)(ws + 4 * 65536);
  float* WEs = (float*)(ws + 5 * 65536);
  float* vecs   = (float*)(ws + 6 * 65536);               // 1.5 KB
  uint4* hbf    = (uint4*)(ws + 1048576);                 // 32 MB (bf16 h_ln)
  unsigned* ndg = (unsigned*)(ws + 1048576 + 33554432);   // 64 MB (bf16 num|den)

  prep_kernel<<<129, 256, 0, stream>>>(sigma, mu, w, erev, ss, smu, sw, serev,
                                       iw, ib, gleak, vleak, cm,
                                       C2r, A2r, WEr, C2s, A2s, WEs, vecs);
  stage_a<<<4096, 256, 84480, stream>>>(x, pre_W, pre_b, plg, plb, hbf);
  sensory_kernel<<<256, 1024, 0, stream>>>(C2s, A2s, WEs, hbf, ndg);
  ltc_scan<<<128, 1024, 0, stream>>>(C2r, A2r, WEr, vecs, ndg,
                                     ow, ob, lng, lnb, hW, hb, out);
}